// Round 5
// baseline (198.972 us; speedup 1.0000x reference)
//
#include <hip/hip_runtime.h>
#include <hip/hip_cooperative_groups.h>
#include <math.h>

namespace cg = cooperative_groups;

#define BB 64
#define SQ 32
#define SD 256
#define HH 128
#define NQ (BB*SQ)   // 2048
#define ND (BB*SD)   // 16384
#define AG 8         // a's per scores block

using short8  = __attribute__((ext_vector_type(8))) short;
using floatx4 = __attribute__((ext_vector_type(4))) float;

__device__ inline unsigned short f2bf(float x) {
  union { float f; unsigned u; } c; c.f = x;
  unsigned r = c.u + 0x7fffu + ((c.u >> 16) & 1u);  // RNE
  return (unsigned short)(r >> 16);
}

// ===========================================================================
// FUSED cooperative kernel: 512 blocks x 256 thr, 2 blocks/CU (LDS 68KB).
//  phase 1 (blocks 0..127): per-sample inv-norm + mask-baked bf16 staging +
//                           avg pairwise similarity  (colsum aliases dt LDS)
//  grid.sync()
//  phase 2 (all 512):       scores[a,b] = max_{s,t} qng[a,s]·dng[b,t]
//  grid.sync()
//  phase 3 (block 0):       loss = mean(lse - diag) + mean(avgq) + mean(avgd)
// ===========================================================================
__global__ __launch_bounds__(256, 2) void fused_kernel(
    const float* __restrict__ qe, const float* __restrict__ de,
    const int* __restrict__ qmask, const int* __restrict__ dmask,
    unsigned short* __restrict__ qng, unsigned short* __restrict__ dng,
    float* __restrict__ avgq, float* __restrict__ avgd,
    float* __restrict__ scores, float* __restrict__ out) {
  __shared__ __align__(16) unsigned short dt[SD][HH + 8];  // 68KB; phase1 aliases
  __shared__ float red[4];
  cg::grid_group grid = cg::this_grid();
  const int tid = threadIdx.x;
  const int blk = blockIdx.x;

  // ---------------- phase 1: prep (blocks 0..127) ----------------
  if (blk < 2 * BB) {
    float* colsum = (float*)dt;          // 8*128 floats = 4KB
    const int g = tid >> 5, c = tid & 31;
    const float* src; const int* msk; unsigned short* dst; int S; float* outp;
    if (blk < BB) {
      src = qe + (size_t)blk * SQ * HH; msk = qmask + blk * SQ;
      dst = qng + (size_t)blk * SQ * HH; S = SQ; outp = avgq + blk;
    } else {
      int b = blk - BB;
      src = de + (size_t)b * SD * HH; msk = dmask + b * SD;
      dst = dng + (size_t)b * SD * HH; S = SD; outp = avgd + b;
    }
    float cs0 = 0.f, cs1 = 0.f, cs2 = 0.f, cs3 = 0.f;
    float a2 = 0.f;
    for (int row = g; row < S; row += 8) {
      float4 v = ((const float4*)(src + (size_t)row * HH))[c];
      float ss = v.x*v.x + v.y*v.y + v.z*v.z + v.w*v.w;
#pragma unroll
      for (int off = 16; off; off >>= 1) ss += __shfl_xor(ss, off);
      float inv = 1.0f / fmaxf(sqrtf(ss), 1e-12f);
      float nx = v.x * inv, ny = v.y * inv, nz = v.z * inv, nw = v.w * inv;
      cs0 += nx; cs1 += ny; cs2 += nz; cs3 += nw;
      a2 += nx*nx + ny*ny + nz*nz + nw*nw;
      float m = (float)msk[row] * inv;
      ushort4 o;
      o.x = f2bf(v.x * m); o.y = f2bf(v.y * m);
      o.z = f2bf(v.z * m); o.w = f2bf(v.w * m);
      ((ushort4*)(dst + (size_t)row * HH))[c] = o;
    }
    *(float4*)&colsum[g * 128 + c * 4] = make_float4(cs0, cs1, cs2, cs3);
    __syncthreads();
    float z = -a2;
    if (tid < 128) {
      float s = 0.f;
#pragma unroll
      for (int gg = 0; gg < 8; gg++) s += colsum[gg * 128 + tid];
      z += s * s;
    }
#pragma unroll
    for (int off = 32; off; off >>= 1) z += __shfl_xor(z, off);
    if ((tid & 63) == 0) red[tid >> 6] = z;
    __syncthreads();
    if (tid == 0) {
      float num = red[0] + red[1] + red[2] + red[3];
      *outp = num / (float)(S * (S - 1));
    }
    __syncthreads();   // everyone done with colsum LDS before phase 2 reuse
  }

  grid.sync();

  // ---------------- phase 2: scores (all 512 blocks) ----------------
  {
    const int bb = blk & 63;
    const int ay = blk >> 6;
    const int m0 = ay * AG * SQ;               // 256 q-rows per block
    const int wave = tid >> 6, lane = tid & 63;
    const int quad = lane >> 4, l16 = lane & 15;

#pragma unroll
    for (int i = 0; i < 16; i++) {             // stage d tile (256 x 128 bf16)
      int idx = i * 256 + tid;
      int row = idx >> 4, c = idx & 15;
      uint4 v = ((const uint4*)(dng + (size_t)(bb * SD + row) * HH))[c];
      *(uint4*)&dt[row][c * 8] = v;
    }

    short8 af[4][4];                            // wave's 64 q-rows, K=128
    const unsigned short* qbase = qng + (size_t)(m0 + wave * 64 + l16) * HH + quad * 8;
#pragma unroll
    for (int mi = 0; mi < 4; mi++)
#pragma unroll
      for (int kc = 0; kc < 4; kc++)
        af[mi][kc] = *(const short8*)(qbase + mi * 16 * HH + kc * 32);

    __syncthreads();

    float m0v = -1e30f, m1v = -1e30f;           // a = ay*AG + wave*2 + {0,1}
    const floatx4 zero = {0.f, 0.f, 0.f, 0.f};
#pragma unroll
    for (int nc = 0; nc < 4; nc++) {
      floatx4 acc[4][4];
#pragma unroll
      for (int mi = 0; mi < 4; mi++)
#pragma unroll
        for (int ni = 0; ni < 4; ni++) acc[mi][ni] = zero;
#pragma unroll
      for (int kc = 0; kc < 4; kc++) {
        short8 bf[4];
#pragma unroll
        for (int ni = 0; ni < 4; ni++)
          bf[ni] = *(const short8*)&dt[nc * 64 + ni * 16 + l16][kc * 32 + quad * 8];
#pragma unroll
        for (int mi = 0; mi < 4; mi++)
#pragma unroll
          for (int ni = 0; ni < 4; ni++)
            acc[mi][ni] = __builtin_amdgcn_mfma_f32_16x16x32_bf16(af[mi][kc], bf[ni], acc[mi][ni], 0, 0, 0);
      }
#pragma unroll
      for (int mi = 0; mi < 4; mi++) {
        float mm = -1e30f;
#pragma unroll
        for (int ni = 0; ni < 4; ni++)
#pragma unroll
          for (int r = 0; r < 4; r++) mm = fmaxf(mm, acc[mi][ni][r]);
        if (mi < 2) m0v = fmaxf(m0v, mm); else m1v = fmaxf(m1v, mm);
      }
    }
#pragma unroll
    for (int off = 32; off; off >>= 1) {
      m0v = fmaxf(m0v, __shfl_xor(m0v, off));
      m1v = fmaxf(m1v, __shfl_xor(m1v, off));
    }
    if (lane == 0) {
      int a = ay * AG + wave * 2;
      scores[(size_t)a * BB + bb]       = m0v;
      scores[(size_t)(a + 1) * BB + bb] = m1v;
    }
  }

  grid.sync();

  // ---------------- phase 3: final (block 0, first wave) ----------------
  if (blk == 0 && tid < BB) {
    int a = tid;
    float row[BB];
    const float4* p = (const float4*)(scores + (size_t)a * BB);
    float mx = -1e30f;
#pragma unroll
    for (int i = 0; i < BB / 4; i++) {
      float4 v = p[i];
      row[i*4+0] = v.x; row[i*4+1] = v.y; row[i*4+2] = v.z; row[i*4+3] = v.w;
      mx = fmaxf(mx, fmaxf(fmaxf(v.x, v.y), fmaxf(v.z, v.w)));
    }
    float sum = 0.f;
#pragma unroll
    for (int b = 0; b < BB; b++) sum += expf(row[b] - mx);
    float v = logf(sum) + mx - row[a] + avgq[a] + avgd[a];
#pragma unroll
    for (int off = 32; off; off >>= 1) v += __shfl_xor(v, off);
    if (a == 0) out[0] = v * (1.0f / 64.0f);
  }
}

// ===========================================================================
// Fallback path (identical to R4's verified 3-kernel pipeline)
// ===========================================================================
__global__ __launch_bounds__(256) void prep_kernel(
    const float* __restrict__ qe, const float* __restrict__ de,
    const int* __restrict__ qmask, const int* __restrict__ dmask,
    unsigned short* __restrict__ qng, unsigned short* __restrict__ dng,
    float* __restrict__ avgq, float* __restrict__ avgd) {
  __shared__ float colsum[8 * 128];
  __shared__ float red[4];
  const int bid = blockIdx.x, tid = threadIdx.x;
  const int g = tid >> 5, c = tid & 31;
  const float* src; const int* msk; unsigned short* dst; int S; float* outp;
  if (bid < BB) {
    src = qe + (size_t)bid * SQ * HH; msk = qmask + bid * SQ;
    dst = qng + (size_t)bid * SQ * HH; S = SQ; outp = avgq + bid;
  } else {
    int b = bid - BB;
    src = de + (size_t)b * SD * HH; msk = dmask + b * SD;
    dst = dng + (size_t)b * SD * HH; S = SD; outp = avgd + b;
  }
  float cs0 = 0.f, cs1 = 0.f, cs2 = 0.f, cs3 = 0.f;
  float a2 = 0.f;
  for (int row = g; row < S; row += 8) {
    float4 v = ((const float4*)(src + (size_t)row * HH))[c];
    float ss = v.x*v.x + v.y*v.y + v.z*v.z + v.w*v.w;
#pragma unroll
    for (int off = 16; off; off >>= 1) ss += __shfl_xor(ss, off);
    float inv = 1.0f / fmaxf(sqrtf(ss), 1e-12f);
    float nx = v.x * inv, ny = v.y * inv, nz = v.z * inv, nw = v.w * inv;
    cs0 += nx; cs1 += ny; cs2 += nz; cs3 += nw;
    a2 += nx*nx + ny*ny + nz*nz + nw*nw;
    float m = (float)msk[row] * inv;
    ushort4 o;
    o.x = f2bf(v.x * m); o.y = f2bf(v.y * m);
    o.z = f2bf(v.z * m); o.w = f2bf(v.w * m);
    ((ushort4*)(dst + (size_t)row * HH))[c] = o;
  }
  *(float4*)&colsum[g * 128 + c * 4] = make_float4(cs0, cs1, cs2, cs3);
  __syncthreads();
  float z = -a2;
  if (tid < 128) {
    float s = 0.f;
#pragma unroll
    for (int gg = 0; gg < 8; gg++) s += colsum[gg * 128 + tid];
    z += s * s;
  }
#pragma unroll
  for (int off = 32; off; off >>= 1) z += __shfl_xor(z, off);
  if ((tid & 63) == 0) red[tid >> 6] = z;
  __syncthreads();
  if (tid == 0) {
    float num = red[0] + red[1] + red[2] + red[3];
    *outp = num / (float)(S * (S - 1));
  }
}

__global__ __launch_bounds__(256, 2) void scores_kernel(
    const unsigned short* __restrict__ qng, const unsigned short* __restrict__ dng,
    float* __restrict__ scores) {
  __shared__ __align__(16) unsigned short dt[SD][HH + 8];
  const int tid = threadIdx.x;
  const int bb = blockIdx.x;
  const int m0 = blockIdx.y * AG * SQ;
  const int wave = tid >> 6, lane = tid & 63;
  const int quad = lane >> 4, l16 = lane & 15;
#pragma unroll
  for (int i = 0; i < 16; i++) {
    int idx = i * 256 + tid;
    int row = idx >> 4, c = idx & 15;
    uint4 v = ((const uint4*)(dng + (size_t)(bb * SD + row) * HH))[c];
    *(uint4*)&dt[row][c * 8] = v;
  }
  short8 af[4][4];
  const unsigned short* qbase = qng + (size_t)(m0 + wave * 64 + l16) * HH + quad * 8;
#pragma unroll
  for (int mi = 0; mi < 4; mi++)
#pragma unroll
    for (int kc = 0; kc < 4; kc++)
      af[mi][kc] = *(const short8*)(qbase + mi * 16 * HH + kc * 32);
  __syncthreads();
  float m0v = -1e30f, m1v = -1e30f;
  const floatx4 zero = {0.f, 0.f, 0.f, 0.f};
#pragma unroll
  for (int nc = 0; nc < 4; nc++) {
    floatx4 acc[4][4];
#pragma unroll
    for (int mi = 0; mi < 4; mi++)
#pragma unroll
      for (int ni = 0; ni < 4; ni++) acc[mi][ni] = zero;
#pragma unroll
    for (int kc = 0; kc < 4; kc++) {
      short8 bf[4];
#pragma unroll
      for (int ni = 0; ni < 4; ni++)
        bf[ni] = *(const short8*)&dt[nc * 64 + ni * 16 + l16][kc * 32 + quad * 8];
#pragma unroll
      for (int mi = 0; mi < 4; mi++)
#pragma unroll
        for (int ni = 0; ni < 4; ni++)
          acc[mi][ni] = __builtin_amdgcn_mfma_f32_16x16x32_bf16(af[mi][kc], bf[ni], acc[mi][ni], 0, 0, 0);
    }
#pragma unroll
    for (int mi = 0; mi < 4; mi++) {
      float mm = -1e30f;
#pragma unroll
      for (int ni = 0; ni < 4; ni++)
#pragma unroll
        for (int r = 0; r < 4; r++) mm = fmaxf(mm, acc[mi][ni][r]);
      if (mi < 2) m0v = fmaxf(m0v, mm); else m1v = fmaxf(m1v, mm);
    }
  }
#pragma unroll
  for (int off = 32; off; off >>= 1) {
    m0v = fmaxf(m0v, __shfl_xor(m0v, off));
    m1v = fmaxf(m1v, __shfl_xor(m1v, off));
  }
  if (lane == 0) {
    int a = blockIdx.y * AG + wave * 2;
    scores[(size_t)a * BB + bb]       = m0v;
    scores[(size_t)(a + 1) * BB + bb] = m1v;
  }
}

__global__ void final_kernel(const float* __restrict__ scores,
                             const float* __restrict__ avgq, const float* __restrict__ avgd,
                             float* __restrict__ out) {
  int a = threadIdx.x;
  float row[BB];
  const float4* p = (const float4*)(scores + (size_t)a * BB);
  float mx = -1e30f;
#pragma unroll
  for (int i = 0; i < BB / 4; i++) {
    float4 v = p[i];
    row[i*4+0] = v.x; row[i*4+1] = v.y; row[i*4+2] = v.z; row[i*4+3] = v.w;
    mx = fmaxf(mx, fmaxf(fmaxf(v.x, v.y), fmaxf(v.z, v.w)));
  }
  float sum = 0.f;
#pragma unroll
  for (int b = 0; b < BB; b++) sum += expf(row[b] - mx);
  float v = logf(sum) + mx - row[a] + avgq[a] + avgd[a];
#pragma unroll
  for (int off = 32; off; off >>= 1) v += __shfl_xor(v, off);
  if (a == 0) out[0] = v * (1.0f / 64.0f);
}

// ---------------------------------------------------------------------------
extern "C" void kernel_launch(void* const* d_in, const int* in_sizes, int n_in,
                              void* d_out, int out_size, void* d_ws, size_t ws_size,
                              hipStream_t stream) {
  const float* qe   = (const float*)d_in[0];
  const float* de   = (const float*)d_in[1];
  const int* qmask  = (const int*)d_in[2];
  const int* dmask  = (const int*)d_in[3];
  float* out = (float*)d_out;
  char* ws = (char*)d_ws;

  float* scores = (float*)(ws);                 // 4096 f
  float* avgq   = (float*)(ws + 16384);         // 64 f
  float* avgd   = (float*)(ws + 16640);         // 64 f
  unsigned short* qng = (unsigned short*)(ws + 32768);           // mask-baked bf16
  unsigned short* dng = (unsigned short*)(ws + 32768 + 524288);

  void* args[] = { (void*)&qe, (void*)&de, (void*)&qmask, (void*)&dmask,
                   (void*)&qng, (void*)&dng, (void*)&avgq, (void*)&avgd,
                   (void*)&scores, (void*)&out };
  hipError_t err = hipLaunchCooperativeKernel((const void*)fused_kernel,
                                              dim3(BB * (BB / AG)), dim3(256),
                                              args, 0, stream);
  if (err != hipSuccess) {
    (void)hipGetLastError();  // clear; deterministic fallback (same every call)
    prep_kernel<<<2 * BB, 256, 0, stream>>>(qe, de, qmask, dmask, qng, dng, avgq, avgd);
    scores_kernel<<<dim3(BB, BB / AG), 256, 0, stream>>>(qng, dng, scores);
    final_kernel<<<1, 64, 0, stream>>>(scores, avgq, avgd, out);
  }
}

// Round 6
// 108.039 us; speedup vs baseline: 1.8417x; 1.8417x over previous
//
#include <hip/hip_runtime.h>
#include <math.h>

#define BB 64
#define SQ 32
#define SD 256
#define HH 128
#define NQ (BB*SQ)   // 2048
#define ND (BB*SD)   // 16384
#define AG 8         // a's per scores block
#define NBLK (BB * (BB / AG))   // 512 scores blocks

using short8  = __attribute__((ext_vector_type(8))) short;
using floatx4 = __attribute__((ext_vector_type(4))) float;

__device__ inline unsigned short f2bf(float x) {
  union { float f; unsigned u; } c; c.f = x;
  unsigned r = c.u + 0x7fffu + ((c.u >> 16) & 1u);  // RNE
  return (unsigned short)(r >> 16);
}

// ---------------------------------------------------------------------------
// Kernel 1: per batch sample, ONE pass over fp32 input:
//   - per-row inv L2 norm
//   - stage mask-baked normalized bf16 rows (qng = qm*q/||q||, dng likewise)
//   - avg pairwise similarity: (||sum_s n_s||^2 - sum_s ||n_s||^2) / (S(S-1))
// Also zeroes the last-block counter used by kernel 2 (block 0 only).
// ---------------------------------------------------------------------------
__global__ __launch_bounds__(256) void prep_kernel(
    const float* __restrict__ qe, const float* __restrict__ de,
    const int* __restrict__ qmask, const int* __restrict__ dmask,
    unsigned short* __restrict__ qng, unsigned short* __restrict__ dng,
    float* __restrict__ avgq, float* __restrict__ avgd,
    unsigned int* __restrict__ cnt) {
  __shared__ float colsum[8 * 128];
  __shared__ float red[4];
  const int bid = blockIdx.x, tid = threadIdx.x;
  if (bid == 0 && tid == 0) *cnt = 0u;   // re-init every call (ws is re-poisoned)
  const int g = tid >> 5, c = tid & 31;
  const float* src; const int* msk; unsigned short* dst; int S; float* outp;
  if (bid < BB) {
    src = qe + (size_t)bid * SQ * HH; msk = qmask + bid * SQ;
    dst = qng + (size_t)bid * SQ * HH; S = SQ; outp = avgq + bid;
  } else {
    int b = bid - BB;
    src = de + (size_t)b * SD * HH; msk = dmask + b * SD;
    dst = dng + (size_t)b * SD * HH; S = SD; outp = avgd + b;
  }
  float cs0 = 0.f, cs1 = 0.f, cs2 = 0.f, cs3 = 0.f;
  float a2 = 0.f;
  for (int row = g; row < S; row += 8) {
    float4 v = ((const float4*)(src + (size_t)row * HH))[c];
    float ss = v.x*v.x + v.y*v.y + v.z*v.z + v.w*v.w;
#pragma unroll
    for (int off = 16; off; off >>= 1) ss += __shfl_xor(ss, off);  // 32-lane row group
    float inv = 1.0f / fmaxf(sqrtf(ss), 1e-12f);
    float nx = v.x * inv, ny = v.y * inv, nz = v.z * inv, nw = v.w * inv;
    cs0 += nx; cs1 += ny; cs2 += nz; cs3 += nw;
    a2 += nx*nx + ny*ny + nz*nz + nw*nw;
    float m = (float)msk[row] * inv;
    ushort4 o;
    o.x = f2bf(v.x * m); o.y = f2bf(v.y * m);
    o.z = f2bf(v.z * m); o.w = f2bf(v.w * m);
    ((ushort4*)(dst + (size_t)row * HH))[c] = o;
  }
  *(float4*)&colsum[g * 128 + c * 4] = make_float4(cs0, cs1, cs2, cs3);
  __syncthreads();
  float z = -a2;
  if (tid < 128) {
    float s = 0.f;
#pragma unroll
    for (int gg = 0; gg < 8; gg++) s += colsum[gg * 128 + tid];
    z += s * s;
  }
#pragma unroll
  for (int off = 32; off; off >>= 1) z += __shfl_xor(z, off);
  if ((tid & 63) == 0) red[tid >> 6] = z;
  __syncthreads();
  if (tid == 0) {
    float num = red[0] + red[1] + red[2] + red[3];
    *outp = num / (float)(S * (S - 1));
  }
}

// ---------------------------------------------------------------------------
// Kernel 2: scores[a,b] = max_{s,t} qng[a,s]·dng[b,t]  (masks pre-baked),
// then the LAST block (device-scope atomic counter) computes the loss:
//   out = mean_a(lse_a - diag_a) + mean(avgq) + mean(avgd)
// Grid 512 blocks (bb = blk&63, ay = blk>>6), 2 blocks/CU (LDS 68KB).
// ---------------------------------------------------------------------------
__global__ __launch_bounds__(256, 2) void scores_final_kernel(
    const unsigned short* __restrict__ qng, const unsigned short* __restrict__ dng,
    float* __restrict__ scores,
    const float* __restrict__ avgq, const float* __restrict__ avgd,
    unsigned int* __restrict__ cnt, float* __restrict__ out) {
  __shared__ __align__(16) unsigned short dt[SD][HH + 8];
  __shared__ int isLast;
  const int tid = threadIdx.x;
  const int bb = blockIdx.x & 63;
  const int ay = blockIdx.x >> 6;
  const int m0 = ay * AG * SQ;                 // 256 q-rows per block
  const int wave = tid >> 6, lane = tid & 63;
  const int quad = lane >> 4, l16 = lane & 15;

  // stage d tile: 4096 chunks x 16B, fully coalesced (1KB per wave-instr).
#pragma unroll
  for (int i = 0; i < 16; i++) {
    int idx = i * 256 + tid;
    int row = idx >> 4, c = idx & 15;
    uint4 v = ((const uint4*)(dng + (size_t)(bb * SD + row) * HH))[c];
    *(uint4*)&dt[row][c * 8] = v;
  }

  // A fragments: wave's 64 M-rows, full K=128. 16 x short8 = 64 VGPRs.
  short8 af[4][4];
  const unsigned short* qbase = qng + (size_t)(m0 + wave * 64 + l16) * HH + quad * 8;
#pragma unroll
  for (int mi = 0; mi < 4; mi++)
#pragma unroll
    for (int kc = 0; kc < 4; kc++)
      af[mi][kc] = *(const short8*)(qbase + mi * 16 * HH + kc * 32);

  __syncthreads();

  float m0v = -1e30f, m1v = -1e30f;            // a = ay*AG + wave*2 + {0,1}
  const floatx4 zero = {0.f, 0.f, 0.f, 0.f};
#pragma unroll
  for (int nc = 0; nc < 4; nc++) {
    floatx4 acc[4][4];
#pragma unroll
    for (int mi = 0; mi < 4; mi++)
#pragma unroll
      for (int ni = 0; ni < 4; ni++) acc[mi][ni] = zero;
#pragma unroll
    for (int kc = 0; kc < 4; kc++) {
      short8 bf[4];
#pragma unroll
      for (int ni = 0; ni < 4; ni++)
        bf[ni] = *(const short8*)&dt[nc * 64 + ni * 16 + l16][kc * 32 + quad * 8];
#pragma unroll
      for (int mi = 0; mi < 4; mi++)
#pragma unroll
        for (int ni = 0; ni < 4; ni++)
          acc[mi][ni] = __builtin_amdgcn_mfma_f32_16x16x32_bf16(af[mi][kc], bf[ni], acc[mi][ni], 0, 0, 0);
    }
#pragma unroll
    for (int mi = 0; mi < 4; mi++) {
      float mm = -1e30f;
#pragma unroll
      for (int ni = 0; ni < 4; ni++)
#pragma unroll
        for (int r = 0; r < 4; r++) mm = fmaxf(mm, acc[mi][ni][r]);
      if (mi < 2) m0v = fmaxf(m0v, mm); else m1v = fmaxf(m1v, mm);
    }
  }
#pragma unroll
  for (int off = 32; off; off >>= 1) {
    m0v = fmaxf(m0v, __shfl_xor(m0v, off));
    m1v = fmaxf(m1v, __shfl_xor(m1v, off));
  }
  if (lane == 0) {
    int a = ay * AG + wave * 2;
    scores[(size_t)a * BB + bb]       = m0v;
    scores[(size_t)(a + 1) * BB + bb] = m1v;
  }
  __syncthreads();   // compiler drains vmcnt before barrier -> stores issued

  // ---- last-block handshake (device-scope; no dispatch-order assumption) ----
  if (tid == 0) {
    __threadfence();                           // release our score writes
    unsigned int old = atomicAdd(cnt, 1u);
    int last = (old == (unsigned)(NBLK - 1));
    if (last) __threadfence();                 // acquire others' score writes
    isLast = last;
  }
  __syncthreads();

  if (isLast && tid < BB) {
    int a = tid;                               // one wave does the 64-row LSE
    const float4* p = (const float4*)(scores + (size_t)a * BB);
    float mx = -1e30f, diag = 0.f;
    float4 row4[BB / 4];
#pragma unroll
    for (int i = 0; i < BB / 4; i++) {
      float4 v = p[i];
      row4[i] = v;
      mx = fmaxf(mx, fmaxf(fmaxf(v.x, v.y), fmaxf(v.z, v.w)));
      if (i == (a >> 2)) {
        int r = a & 3;
        diag = (r == 0) ? v.x : (r == 1) ? v.y : (r == 2) ? v.z : v.w;
      }
    }
    float sum = 0.f;
#pragma unroll
    for (int i = 0; i < BB / 4; i++) {
      sum += expf(row4[i].x - mx) + expf(row4[i].y - mx)
           + expf(row4[i].z - mx) + expf(row4[i].w - mx);
    }
    float v = logf(sum) + mx - diag + avgq[a] + avgd[a];
#pragma unroll
    for (int off = 32; off; off >>= 1) v += __shfl_xor(v, off);
    if (a == 0) out[0] = v * (1.0f / 64.0f);
  }
}

// ---------------------------------------------------------------------------
extern "C" void kernel_launch(void* const* d_in, const int* in_sizes, int n_in,
                              void* d_out, int out_size, void* d_ws, size_t ws_size,
                              hipStream_t stream) {
  const float* qe   = (const float*)d_in[0];
  const float* de   = (const float*)d_in[1];
  const int* qmask  = (const int*)d_in[2];
  const int* dmask  = (const int*)d_in[3];
  float* out = (float*)d_out;
  char* ws = (char*)d_ws;

  float* scores      = (float*)(ws);            // 4096 f
  float* avgq        = (float*)(ws + 16384);    // 64 f
  float* avgd        = (float*)(ws + 16640);    // 64 f
  unsigned int* cnt  = (unsigned int*)(ws + 20480);
  unsigned short* qng = (unsigned short*)(ws + 32768);           // mask-baked bf16
  unsigned short* dng = (unsigned short*)(ws + 32768 + 524288);

  prep_kernel<<<2 * BB, 256, 0, stream>>>(qe, de, qmask, dmask, qng, dng, avgq, avgd, cnt);
  scores_final_kernel<<<NBLK, 256, 0, stream>>>(qng, dng, scores, avgq, avgd, cnt, out);
}

// Round 7
// 99.513 us; speedup vs baseline: 1.9994x; 1.0857x over previous
//
#include <hip/hip_runtime.h>
#include <math.h>

#define BB 64
#define SQ 32
#define SD 256
#define HH 128
#define NQ (BB*SQ)   // 2048
#define ND (BB*SD)   // 16384
#define AG 8         // a's per scores block

using short8  = __attribute__((ext_vector_type(8))) short;
using floatx4 = __attribute__((ext_vector_type(4))) float;

__device__ inline unsigned short f2bf(float x) {
  union { float f; unsigned u; } c; c.f = x;
  unsigned r = c.u + 0x7fffu + ((c.u >> 16) & 1u);  // RNE
  return (unsigned short)(r >> 16);
}

// ---------------------------------------------------------------------------
// Kernel 1 (fused): per batch sample, in ONE pass over the fp32 input:
//   - per-row inv L2 norm
//   - stage mask-baked normalized bf16 rows (qng = qm*q/||q||, dng likewise)
//   - avg pairwise similarity: (||sum_s n_s||^2 - sum_s ||n_s||^2) / (S(S-1))
// Grid: 128 blocks (0..63 q batches, 64..127 d batches), 256 threads =
// 8 row-groups x 32 lanes (float4/lane covers H=128).
// ---------------------------------------------------------------------------
__global__ __launch_bounds__(256) void prep_kernel(
    const float* __restrict__ qe, const float* __restrict__ de,
    const int* __restrict__ qmask, const int* __restrict__ dmask,
    unsigned short* __restrict__ qng, unsigned short* __restrict__ dng,
    float* __restrict__ avgq, float* __restrict__ avgd) {
  __shared__ float colsum[8 * 128];   // [group][col]
  __shared__ float red[4];
  const int bid = blockIdx.x, tid = threadIdx.x;
  const int g = tid >> 5, c = tid & 31;

  const float* src; const int* msk; unsigned short* dst; int S; float* outp;
  if (bid < BB) {
    src = qe + (size_t)bid * SQ * HH; msk = qmask + bid * SQ;
    dst = qng + (size_t)bid * SQ * HH; S = SQ; outp = avgq + bid;
  } else {
    int b = bid - BB;
    src = de + (size_t)b * SD * HH; msk = dmask + b * SD;
    dst = dng + (size_t)b * SD * HH; S = SD; outp = avgd + b;
  }

  float cs0 = 0.f, cs1 = 0.f, cs2 = 0.f, cs3 = 0.f;  // per-col partial sums
  float a2 = 0.f;                                    // partial sum ||n_s||^2
  for (int row = g; row < S; row += 8) {
    float4 v = ((const float4*)(src + (size_t)row * HH))[c];
    float ss = v.x*v.x + v.y*v.y + v.z*v.z + v.w*v.w;
#pragma unroll
    for (int off = 16; off; off >>= 1) ss += __shfl_xor(ss, off);  // 32-lane group
    float inv = 1.0f / fmaxf(sqrtf(ss), 1e-12f);
    float nx = v.x * inv, ny = v.y * inv, nz = v.z * inv, nw = v.w * inv;
    cs0 += nx; cs1 += ny; cs2 += nz; cs3 += nw;
    a2 += nx*nx + ny*ny + nz*nz + nw*nw;
    float m = (float)msk[row] * inv;
    ushort4 o;
    o.x = f2bf(v.x * m); o.y = f2bf(v.y * m);
    o.z = f2bf(v.z * m); o.w = f2bf(v.w * m);
    ((ushort4*)(dst + (size_t)row * HH))[c] = o;
  }
  // store col partials: contiguous float4 per lane -> conflict-free b128
  *(float4*)&colsum[g * 128 + c * 4] = make_float4(cs0, cs1, cs2, cs3);
  __syncthreads();

  float z = -a2;
  if (tid < 128) {
    float s = 0.f;
#pragma unroll
    for (int gg = 0; gg < 8; gg++) s += colsum[gg * 128 + tid];
    z += s * s;
  }
#pragma unroll
  for (int off = 32; off; off >>= 1) z += __shfl_xor(z, off);
  if ((tid & 63) == 0) red[tid >> 6] = z;
  __syncthreads();
  if (tid == 0) {
    float num = red[0] + red[1] + red[2] + red[3];
    *outp = num / (float)(S * (S - 1));
  }
}

// ---------------------------------------------------------------------------
// Kernel 2: scores[a,b] = max_{s,t} qng[a,s]·dng[b,t]  (masks pre-baked).
// Grid (BB, BB/AG) = (64,8) = 512 blocks, 2 blocks/CU (LDS 68KB).
// d-tile (256x128 bf16) in LDS shared by 4 waves; each wave holds its 64
// q-rows (2 a's) as resident A-fragments in VGPRs. N in 4 chunks of 64,
// acc[4][4]; max folds per chunk; each wave writes its 2 scores directly.
// ---------------------------------------------------------------------------
__global__ __launch_bounds__(256, 2) void scores_kernel(
    const unsigned short* __restrict__ qng, const unsigned short* __restrict__ dng,
    float* __restrict__ scores) {
  __shared__ __align__(16) unsigned short dt[SD][HH + 8];
  const int tid = threadIdx.x;
  const int bb = blockIdx.x;
  const int m0 = blockIdx.y * AG * SQ;         // 256 q-rows per block
  const int wave = tid >> 6, lane = tid & 63;
  const int quad = lane >> 4, l16 = lane & 15;

  // stage d tile: 4096 chunks x 16B, fully coalesced (1KB per wave-instr).
#pragma unroll
  for (int i = 0; i < 16; i++) {
    int idx = i * 256 + tid;
    int row = idx >> 4, c = idx & 15;
    uint4 v = ((const uint4*)(dng + (size_t)(bb * SD + row) * HH))[c];
    *(uint4*)&dt[row][c * 8] = v;
  }

  // A fragments: wave's 64 M-rows, full K=128. 16 x short8 = 64 VGPRs.
  short8 af[4][4];
  const unsigned short* qbase = qng + (size_t)(m0 + wave * 64 + l16) * HH + quad * 8;
#pragma unroll
  for (int mi = 0; mi < 4; mi++)
#pragma unroll
    for (int kc = 0; kc < 4; kc++)
      af[mi][kc] = *(const short8*)(qbase + mi * 16 * HH + kc * 32);

  __syncthreads();

  float m0v = -1e30f, m1v = -1e30f;   // per-a maxima (a = blockIdx.y*AG + wave*2 + {0,1})
  const floatx4 zero = {0.f, 0.f, 0.f, 0.f};

#pragma unroll
  for (int nc = 0; nc < 4; nc++) {
    floatx4 acc[4][4];
#pragma unroll
    for (int mi = 0; mi < 4; mi++)
#pragma unroll
      for (int ni = 0; ni < 4; ni++) acc[mi][ni] = zero;
#pragma unroll
    for (int kc = 0; kc < 4; kc++) {
      short8 bf[4];
#pragma unroll
      for (int ni = 0; ni < 4; ni++)
        bf[ni] = *(const short8*)&dt[nc * 64 + ni * 16 + l16][kc * 32 + quad * 8];
#pragma unroll
      for (int mi = 0; mi < 4; mi++)
#pragma unroll
        for (int ni = 0; ni < 4; ni++)
          acc[mi][ni] = __builtin_amdgcn_mfma_f32_16x16x32_bf16(af[mi][kc], bf[ni], acc[mi][ni], 0, 0, 0);
    }
#pragma unroll
    for (int mi = 0; mi < 4; mi++) {
      float mm = -1e30f;
#pragma unroll
      for (int ni = 0; ni < 4; ni++)
#pragma unroll
        for (int r = 0; r < 4; r++) mm = fmaxf(mm, acc[mi][ni][r]);
      if (mi < 2) m0v = fmaxf(m0v, mm); else m1v = fmaxf(m1v, mm);
    }
  }
#pragma unroll
  for (int off = 32; off; off >>= 1) {
    m0v = fmaxf(m0v, __shfl_xor(m0v, off));
    m1v = fmaxf(m1v, __shfl_xor(m1v, off));
  }
  if (lane == 0) {
    int a = blockIdx.y * AG + wave * 2;
    scores[(size_t)a * BB + bb]       = m0v;
    scores[(size_t)(a + 1) * BB + bb] = m1v;
  }
}

// ---------------------------------------------------------------------------
// Kernel 3: loss = mean_a(lse_a - diag_a) + mean(avgq) + mean(avgd)
// ---------------------------------------------------------------------------
__global__ void final_kernel(const float* __restrict__ scores,
                             const float* __restrict__ avgq, const float* __restrict__ avgd,
                             float* __restrict__ out) {
  int a = threadIdx.x;  // 0..63, one wave
  float row[BB];
  const float4* p = (const float4*)(scores + (size_t)a * BB);
  float mx = -1e30f;
#pragma unroll
  for (int i = 0; i < BB / 4; i++) {
    float4 v = p[i];
    row[i*4+0] = v.x; row[i*4+1] = v.y; row[i*4+2] = v.z; row[i*4+3] = v.w;
    mx = fmaxf(mx, fmaxf(fmaxf(v.x, v.y), fmaxf(v.z, v.w)));
  }
  float sum = 0.f;
#pragma unroll
  for (int b = 0; b < BB; b++) sum += expf(row[b] - mx);
  float v = logf(sum) + mx - row[a] + avgq[a] + avgd[a];
#pragma unroll
  for (int off = 32; off; off >>= 1) v += __shfl_xor(v, off);
  if (a == 0) out[0] = v * (1.0f / 64.0f);
}

// ---------------------------------------------------------------------------
extern "C" void kernel_launch(void* const* d_in, const int* in_sizes, int n_in,
                              void* d_out, int out_size, void* d_ws, size_t ws_size,
                              hipStream_t stream) {
  const float* qe   = (const float*)d_in[0];
  const float* de   = (const float*)d_in[1];
  const int* qmask  = (const int*)d_in[2];
  const int* dmask  = (const int*)d_in[3];
  float* out = (float*)d_out;
  char* ws = (char*)d_ws;

  float* scores = (float*)(ws);                 // 4096 f
  float* avgq   = (float*)(ws + 16384);         // 64 f
  float* avgd   = (float*)(ws + 16640);         // 64 f
  unsigned short* qng = (unsigned short*)(ws + 32768);           // 2048*128 bf16 (mask-baked)
  unsigned short* dng = (unsigned short*)(ws + 32768 + 524288);  // 16384*128 bf16 (mask-baked)

  prep_kernel<<<2 * BB, 256, 0, stream>>>(qe, de, qmask, dmask, qng, dng, avgq, avgd);
  scores_kernel<<<dim3(BB, BB / AG), 256, 0, stream>>>(qng, dng, scores);
  final_kernel<<<1, 64, 0, stream>>>(scores, avgq, avgd, out);
}